// Round 5
// baseline (14885.480 us; speedup 1.0000x reference)
//
#include <hip/hip_runtime.h>
#include <hip/hip_bf16.h>

#define T_STEPS 100
#define NG 4096
#define NP 512

typedef __bf16 bf16x8 __attribute__((ext_vector_type(8)));
typedef float f32x4 __attribute__((ext_vector_type(4)));

__device__ __forceinline__ f32x4 mfma_bf16(bf16x8 a, bf16x8 b, f32x4 c) {
  return __builtin_amdgcn_mfma_f32_16x16x32_bf16(a, b, c, 0, 0, 0);
}

// ---------------- f32 -> bf16 conversion, 8 elems/thread ----------------
__global__ __launch_bounds__(256) void cvt_bf16_kernel(const float* __restrict__ in,
                                                       __hip_bfloat16* __restrict__ out,
                                                       int n8) {
  int i = blockIdx.x * 256 + threadIdx.x;
  if (i >= n8) return;
  const float4* p = reinterpret_cast<const float4*>(in) + (size_t)i * 2;
  float4 f0 = p[0], f1 = p[1];
  union { __hip_bfloat16 h[8]; uint4 u; } z;
  z.h[0] = __float2bfloat16(f0.x); z.h[1] = __float2bfloat16(f0.y);
  z.h[2] = __float2bfloat16(f0.z); z.h[3] = __float2bfloat16(f0.w);
  z.h[4] = __float2bfloat16(f1.x); z.h[5] = __float2bfloat16(f1.y);
  z.h[6] = __float2bfloat16(f1.z); z.h[7] = __float2bfloat16(f1.w);
  *(reinterpret_cast<uint4*>(out) + i) = z.u;
}

// ---------------- encoder: h0 = p0 @ W_enc^T  -> bf16 -------------------
__global__ __launch_bounds__(256) void encoder_kernel(const float* __restrict__ p0,
                                                      const float* __restrict__ Wenc,
                                                      __hip_bfloat16* __restrict__ h0) {
  __shared__ float sp[64 * 129];
  const int tid = threadIdx.x;
  const int nb = blockIdx.x * 16;
  const int b = tid & 63;
  const int jg = tid >> 6;
  float acc[4] = {0.f, 0.f, 0.f, 0.f};
  for (int kc = 0; kc < NP; kc += 128) {
    __syncthreads();
    #pragma unroll
    for (int i = 0; i < 32; ++i) {
      int e = tid + i * 256;
      int bb = e >> 7, kk = e & 127;
      sp[bb * 129 + kk] = p0[bb * NP + kc + kk];
    }
    __syncthreads();
    for (int kk = 0; kk < 128; ++kk) {
      float pv = sp[b * 129 + kk];
      #pragma unroll
      for (int jj = 0; jj < 4; ++jj)
        acc[jj] += pv * Wenc[(size_t)(nb + jg * 4 + jj) * NP + kc + kk];
    }
  }
  #pragma unroll
  for (int jj = 0; jj < 4; ++jj)
    h0[(size_t)b * NG + nb + jg * 4 + jj] = __float2bfloat16(acc[jj]);
}

// ---------------- fused RNN step: split-k GEMM + last-block epilogue ----
// grid (128 ng, 8 kq) = 1024 blocks (4/CU, 16 waves/CU), block 256 = 4 waves.
// Wave ms owns b-rows [16ms,16ms+16); block owns n-cols [32ng,32ng+32),
// k-slice [512kq, +512). Partials -> zpart[kq][64][4096] (f32).
// Each block: stores, __threadfence (device release), atomicAdd counter;
// the 8th arriving block for an ng re-reads all 8 partials (fixed kq order
// -> deterministic), applies v@Win^T + recurrence, writes gs[t] bf16.
__global__ __launch_bounds__(256, 4) void rnn_fused_kernel(
    const __hip_bfloat16* __restrict__ A, int strideA,
    const __hip_bfloat16* __restrict__ Wh,
    const float* __restrict__ v, const float* __restrict__ Win,
    float* __restrict__ zpart, int* __restrict__ cnt,
    float* __restrict__ vv, float* __restrict__ zp,
    __hip_bfloat16* __restrict__ gs, int t) {
  const int tid = threadIdx.x;
  const int lane = tid & 63;
  const int ms = tid >> 6;            // wave id = b-strip
  const int ng = blockIdx.x, kq = blockIdx.y;
  const int r = lane & 15;
  const int kg = lane >> 4;
  const int kbase = kq * 512 + kg * 8;
  const int n0 = ng * 32;

  const __hip_bfloat16* pA = A + (size_t)(ms * 16 + r) * strideA + kbase;
  const __hip_bfloat16* pB0 = Wh + (size_t)(n0 + r) * NG + kbase;
  const __hip_bfloat16* pB1 = pB0 + (size_t)16 * NG;

  f32x4 acc0{}, acc1{};
  bf16x8 cA = *(const bf16x8*)(pA);
  bf16x8 cB0 = *(const bf16x8*)(pB0);
  bf16x8 cB1 = *(const bf16x8*)(pB1);
  #pragma unroll
  for (int it = 0; it < 16; ++it) {
    bf16x8 nA, nB0, nB1;
    if (it < 15) {
      nA = *(const bf16x8*)(pA + (it + 1) * 32);
      nB0 = *(const bf16x8*)(pB0 + (it + 1) * 32);
      nB1 = *(const bf16x8*)(pB1 + (it + 1) * 32);
    }
    acc0 = mfma_bf16(cA, cB0, acc0);
    acc1 = mfma_bf16(cA, cB1, acc1);
    if (it < 15) { cA = nA; cB0 = nB0; cB1 = nB1; }
  }

  // store partial: row b = ms*16 + kg*4 + j, col n = n0 + {r, r+16}
  float* zb = zpart + ((size_t)(kq * 64 + ms * 16 + kg * 4) << 12) + n0 + r;
  #pragma unroll
  for (int j = 0; j < 4; ++j) {
    zb[(size_t)j * NG]      = acc0[j];
    zb[(size_t)j * NG + 16] = acc1[j];
  }

  __threadfence();                    // release: partials visible device-wide
  __syncthreads();                    // all waves' stores+fences done
  __shared__ int sLast;
  if (tid == 0) sLast = (atomicAdd(&cnt[ng], 1) == 7) ? 1 : 0;
  __syncthreads();
  if (!sLast) return;
  __threadfence();                    // acquire: see other blocks' partials

  // ---- epilogue: this block reduces its 64 b x 32 n panel ----
  const int nl = (tid & 7) * 4;       // n offset within panel
  const int bb = (tid >> 3) * 2;      // 2 b rows per thread
  const int n = n0 + nl;
  const float4 wA = *(const float4*)(Win + 2 * n);
  const float4 wB = *(const float4*)(Win + 2 * n + 4);
  #pragma unroll
  for (int u = 0; u < 2; ++u) {
    const int b = bb + u;
    f32x4 s{};
    #pragma unroll
    for (int q = 0; q < 8; ++q)
      s += *(const f32x4*)(zpart + ((size_t)(q * 64 + b) << 12) + n);
    float2 vt = *(const float2*)(v + (b * T_STEPS + t) * 2);
    f32x4 z;
    z[0] = s[0] + vt.x * wA.x + vt.y * wA.y;
    z[1] = s[1] + vt.x * wA.z + vt.y * wA.w;
    z[2] = s[2] + vt.x * wB.x + vt.y * wB.y;
    z[3] = s[3] + vt.x * wB.z + vt.y * wB.w;
    f32x4 vvo = *(const f32x4*)(vv + (size_t)b * NG + n);
    f32x4 zpo = *(const f32x4*)(zp + (size_t)b * NG + n);
    f32x4 vvn;
    union { __hip_bfloat16 h[4]; uint2 u2; } o;
    #pragma unroll
    for (int j = 0; j < 4; ++j) {
      z[j] -= 0.5f * vvo[j];                          // z uses OLD vv
      vvn[j] = fmaxf(vvo[j] + 0.1f * (zpo[j] - vvo[j]), 0.f);
      o.h[j] = __float2bfloat16(fmaxf(z[j], 0.f));
    }
    *(f32x4*)(vv + (size_t)b * NG + n) = vvn;
    *(f32x4*)(zp + (size_t)b * NG + n) = z;           // pre-relu z
    *(uint2*)(gs + (size_t)(b * T_STEPS + t) * NG + n) = o.u2;
  }
}

// ---------------- decoder: logits = gs @ W_dec^T ------------------------
// grid (8 n-tiles, 100 m-tiles) -- n FASTEST: XCD i owns n-tile i, so its
// 512 KB Wd panel stays L2-resident; gs streams once through L3.
// Block 64m x 64n, 4 waves 32m x 32n (2x2 frags: 4 MFMA per 4 loads).
__global__ __launch_bounds__(256, 4) void decoder_kernel(
    const __hip_bfloat16* __restrict__ gs,
    const __hip_bfloat16* __restrict__ Wd,
    float* __restrict__ out) {
  const int lane = threadIdx.x & 63;
  const int w = threadIdx.x >> 6;
  const int ms = w >> 1, ns = w & 1;
  const int m0 = blockIdx.y * 64 + ms * 32;
  const int n0 = blockIdx.x * 64 + ns * 32;
  const int r = lane & 15;
  const int kg = lane >> 4;
  const __hip_bfloat16* pA0 = gs + (size_t)(m0 + r) * NG + kg * 8;
  const __hip_bfloat16* pA1 = pA0 + (size_t)16 * NG;
  const __hip_bfloat16* pB0 = Wd + (size_t)(n0 + r) * NG + kg * 8;
  const __hip_bfloat16* pB1 = pB0 + (size_t)16 * NG;

  f32x4 a00{}, a01{}, a10{}, a11{};
  bf16x8 cA0 = *(const bf16x8*)pA0;
  bf16x8 cA1 = *(const bf16x8*)pA1;
  bf16x8 cB0 = *(const bf16x8*)pB0;
  bf16x8 cB1 = *(const bf16x8*)pB1;
  #pragma unroll 8
  for (int c = 0; c < 127; ++c) {
    bf16x8 nA0 = *(const bf16x8*)(pA0 + (c + 1) * 32);
    bf16x8 nA1 = *(const bf16x8*)(pA1 + (c + 1) * 32);
    bf16x8 nB0 = *(const bf16x8*)(pB0 + (c + 1) * 32);
    bf16x8 nB1 = *(const bf16x8*)(pB1 + (c + 1) * 32);
    a00 = mfma_bf16(cA0, cB0, a00);
    a01 = mfma_bf16(cA0, cB1, a01);
    a10 = mfma_bf16(cA1, cB0, a10);
    a11 = mfma_bf16(cA1, cB1, a11);
    cA0 = nA0; cA1 = nA1; cB0 = nB0; cB1 = nB1;
  }
  a00 = mfma_bf16(cA0, cB0, a00);
  a01 = mfma_bf16(cA0, cB1, a01);
  a10 = mfma_bf16(cA1, cB0, a10);
  a11 = mfma_bf16(cA1, cB1, a11);

  #pragma unroll
  for (int j = 0; j < 4; ++j) {
    float* po0 = out + (size_t)(m0 + kg * 4 + j) * NP + n0;
    float* po1 = out + (size_t)(m0 + 16 + kg * 4 + j) * NP + n0;
    po0[r]      = a00[j];
    po0[r + 16] = a01[j];
    po1[r]      = a10[j];
    po1[r + 16] = a11[j];
  }
}

// ---------------- log_softmax over rows of 512 (in place) ---------------
__global__ __launch_bounds__(256) void logsoftmax_kernel(float* __restrict__ out) {
  float* row = out + (size_t)blockIdx.x * NP;
  const int tid = threadIdx.x;
  const int lane = tid & 63, wid = tid >> 6;
  float x0 = row[tid], x1 = row[tid + 256];
  float m = fmaxf(x0, x1);
  #pragma unroll
  for (int off = 32; off >= 1; off >>= 1) m = fmaxf(m, __shfl_xor(m, off));
  __shared__ float sred[8];
  if (lane == 0) sred[wid] = m;
  __syncthreads();
  m = fmaxf(fmaxf(sred[0], sred[1]), fmaxf(sred[2], sred[3]));
  float e = __expf(x0 - m) + __expf(x1 - m);
  #pragma unroll
  for (int off = 32; off >= 1; off >>= 1) e += __shfl_xor(e, off);
  if (lane == 0) sred[4 + wid] = e;
  __syncthreads();
  float lse = m + __logf(sred[4] + sred[5] + sred[6] + sred[7]);
  row[tid] = x0 - lse;
  row[tid + 256] = x1 - lse;
}

extern "C" void kernel_launch(void* const* d_in, const int* in_sizes, int n_in,
                              void* d_out, int out_size, void* d_ws, size_t ws_size,
                              hipStream_t stream) {
  const float* v    = (const float*)d_in[0];  // [64,100,2]
  const float* p0   = (const float*)d_in[1];  // [64,512]
  const float* Wenc = (const float*)d_in[2];  // [4096,512]
  const float* Win  = (const float*)d_in[3];  // [4096,2]
  const float* Wh   = (const float*)d_in[4];  // [4096,4096]
  const float* Wdec = (const float*)d_in[5];  // [512,4096]
  float* out = (float*)d_out;                 // [64,100,512]

  char* ws = (char*)d_ws;
  __hip_bfloat16* gs      = (__hip_bfloat16*)(ws);               // 52,428,800
  __hip_bfloat16* Wh_bf   = (__hip_bfloat16*)(ws + 52428800);    // 33,554,432
  float*          zpart   = (float*)(ws + 85983232);             //  8,388,608
  __hip_bfloat16* Wdec_bf = (__hip_bfloat16*)(ws + 85983232);    // aliases zpart (used after RNN)
  float*          vv      = (float*)(ws + 94371840);             //  1,048,576
  float*          zp      = (float*)(ws + 95420416);             //  1,048,576
  __hip_bfloat16* h0_bf   = (__hip_bfloat16*)(ws + 96468992);    //    524,288
  int*            cnt     = (int*)(ws + 96993280);               //     51,200
  // total 97,044,480 B

  hipMemsetAsync(vv, 0, 2 * 1048576, stream);   // vv + zp (contiguous)
  hipMemsetAsync(cnt, 0, T_STEPS * 128 * sizeof(int), stream);
  cvt_bf16_kernel<<<8192, 256, 0, stream>>>(Wh, Wh_bf, 2097152);
  encoder_kernel<<<256, 256, 0, stream>>>(p0, Wenc, h0_bf);

  for (int t = 0; t < T_STEPS; ++t) {
    const __hip_bfloat16* A = (t == 0) ? h0_bf : (gs + (size_t)(t - 1) * NG);
    int sA = (t == 0) ? NG : T_STEPS * NG;
    rnn_fused_kernel<<<dim3(128, 8), 256, 0, stream>>>(
        A, sA, Wh_bf, v, Win, zpart, cnt + t * 128, vv, zp, gs, t);
  }

  cvt_bf16_kernel<<<1024, 256, 0, stream>>>(Wdec, Wdec_bf, 262144);  // after RNN (aliases zpart)
  decoder_kernel<<<dim3(8, 100), 256, 0, stream>>>(gs, Wdec_bf, out);
  logsoftmax_kernel<<<6400, 256, 0, stream>>>(out);
}

// Round 6
// 3359.269 us; speedup vs baseline: 4.4312x; 4.4312x over previous
//
#include <hip/hip_runtime.h>
#include <hip/hip_bf16.h>

#define T_STEPS 100
#define NG 4096
#define NP 512

typedef __bf16 bf16x8 __attribute__((ext_vector_type(8)));
typedef float f32x4 __attribute__((ext_vector_type(4)));

__device__ __forceinline__ f32x4 mfma_bf16(bf16x8 a, bf16x8 b, f32x4 c) {
  return __builtin_amdgcn_mfma_f32_16x16x32_bf16(a, b, c, 0, 0, 0);
}

// ---------------- f32 -> bf16 conversion, 8 elems/thread ----------------
__global__ __launch_bounds__(256) void cvt_bf16_kernel(const float* __restrict__ in,
                                                       __hip_bfloat16* __restrict__ out,
                                                       int n8) {
  int i = blockIdx.x * 256 + threadIdx.x;
  if (i >= n8) return;
  const float4* p = reinterpret_cast<const float4*>(in) + (size_t)i * 2;
  float4 f0 = p[0], f1 = p[1];
  union { __hip_bfloat16 h[8]; uint4 u; } z;
  z.h[0] = __float2bfloat16(f0.x); z.h[1] = __float2bfloat16(f0.y);
  z.h[2] = __float2bfloat16(f0.z); z.h[3] = __float2bfloat16(f0.w);
  z.h[4] = __float2bfloat16(f1.x); z.h[5] = __float2bfloat16(f1.y);
  z.h[6] = __float2bfloat16(f1.z); z.h[7] = __float2bfloat16(f1.w);
  *(reinterpret_cast<uint4*>(out) + i) = z.u;
}

// ---------------- encoder: h0 = p0 @ W_enc^T  -> bf16 -------------------
__global__ __launch_bounds__(256) void encoder_kernel(const float* __restrict__ p0,
                                                      const float* __restrict__ Wenc,
                                                      __hip_bfloat16* __restrict__ h0) {
  __shared__ float sp[64 * 129];
  const int tid = threadIdx.x;
  const int nb = blockIdx.x * 16;
  const int b = tid & 63;
  const int jg = tid >> 6;
  float acc[4] = {0.f, 0.f, 0.f, 0.f};
  for (int kc = 0; kc < NP; kc += 128) {
    __syncthreads();
    #pragma unroll
    for (int i = 0; i < 32; ++i) {
      int e = tid + i * 256;
      int bb = e >> 7, kk = e & 127;
      sp[bb * 129 + kk] = p0[bb * NP + kc + kk];
    }
    __syncthreads();
    for (int kk = 0; kk < 128; ++kk) {
      float pv = sp[b * 129 + kk];
      #pragma unroll
      for (int jj = 0; jj < 4; ++jj)
        acc[jj] += pv * Wenc[(size_t)(nb + jg * 4 + jj) * NP + kc + kk];
    }
  }
  #pragma unroll
  for (int jj = 0; jj < 4; ++jj)
    h0[(size_t)b * NG + nb + jg * 4 + jj] = __float2bfloat16(acc[jj]);
}

// ---------------- RNN step: full-K in-block, fused epilogue -------------
// grid (128 ng, 4 bq) = 512 blocks (2/CU, 16 waves/CU), block 512 = 8 waves.
// Wave (kh = w>>1 in 0..3: k-quarter of 1024; nh = w&1: 16-n half).
// Block tile: 16 b x 32 n x 4096 k. k-quarters reduced via 6 KB LDS
// (layout [q][nh][j][lane] -> conflict-free b32). Epilogue in-block:
// v@Win^T + vv/zp recurrence (global f32, stable (b,n)->block mapping).
// No cross-block comms. XCD: linear%8 = ng%8 -> each XCD re-reads the same
// 4 MiB Wh slice every step => L2-resident across launches.
__global__ __launch_bounds__(512, 4) void rnn_step_kernel(
    const __hip_bfloat16* __restrict__ A, int strideA,
    const __hip_bfloat16* __restrict__ Wh,
    const float* __restrict__ v, const float* __restrict__ Win,
    float* __restrict__ vv, float* __restrict__ zp,
    __hip_bfloat16* __restrict__ gs, int t) {
  __shared__ float sred[3][2][4][64];
  const int tid = threadIdx.x;
  const int lane = tid & 63;
  const int w = tid >> 6;
  const int kh = w >> 1;          // k-quarter
  const int nh = w & 1;           // n-half
  const int r = lane & 15;
  const int kg = lane >> 4;
  const int n0 = blockIdx.x * 32 + nh * 16;
  const int b0 = blockIdx.y * 16;
  const int kbase = kh * 1024 + kg * 8;

  const __hip_bfloat16* pA = A + (size_t)(b0 + r) * strideA + kbase;
  const __hip_bfloat16* pB = Wh + (size_t)(n0 + r) * NG + kbase;

  f32x4 acc0{}, acc1{};
  bf16x8 cA = *(const bf16x8*)pA;
  bf16x8 cB = *(const bf16x8*)pB;
  #pragma unroll
  for (int it = 0; it < 32; ++it) {
    bf16x8 nA, nB;
    if (it < 31) {
      nA = *(const bf16x8*)(pA + (it + 1) * 32);
      nB = *(const bf16x8*)(pB + (it + 1) * 32);
    }
    if (it & 1) acc1 = mfma_bf16(cA, cB, acc1);
    else        acc0 = mfma_bf16(cA, cB, acc0);
    if (it < 31) { cA = nA; cB = nB; }
  }
  acc0 += acc1;

  if (kh > 0) {
    #pragma unroll
    for (int j = 0; j < 4; ++j) sred[kh - 1][nh][j][lane] = acc0[j];
  }
  __syncthreads();
  if (kh == 0) {
    const int n = n0 + r;
    const float wi0 = Win[2 * n], wi1 = Win[2 * n + 1];
    #pragma unroll
    for (int j = 0; j < 4; ++j) {
      const int b = b0 + kg * 4 + j;
      float zv = acc0[j] + sred[0][nh][j][lane] + sred[1][nh][j][lane]
                        + sred[2][nh][j][lane];
      float2 vt = *(const float2*)(v + (b * T_STEPS + t) * 2);
      zv += vt.x * wi0 + vt.y * wi1;
      const size_t idx = (size_t)b * NG + n;
      const float vvo = vv[idx], zpo = zp[idx];
      zv -= 0.5f * vvo;                              // z uses OLD vv
      const float vvn = fmaxf(vvo + 0.1f * (zpo - vvo), 0.f);
      vv[idx] = vvn;
      zp[idx] = zv;                                  // pre-relu z
      gs[(size_t)(b * T_STEPS + t) * NG + n] = __float2bfloat16(fmaxf(zv, 0.f));
    }
  }
}

// ---------------- decoder + fused log_softmax ---------------------------
// grid 400 m-tiles of 16 rows; block 512 = 8 waves, wave nh owns 64 n-cols
// (4 frags). gs read exactly once; Wd (4 MiB) L2-resident per XCD.
// Logits staged in 32 KB static LDS, then per-row shuffle log_softmax.
__global__ __launch_bounds__(512, 2) void decoder_softmax_kernel(
    const __hip_bfloat16* __restrict__ gs,
    const __hip_bfloat16* __restrict__ Wd,
    float* __restrict__ out) {
  __shared__ float sC[16][NP];
  const int tid = threadIdx.x;
  const int lane = tid & 63;
  const int nh = tid >> 6;        // wave id = n-chunk of 64
  const int m0 = blockIdx.x * 16;
  const int r = lane & 15;
  const int kg = lane >> 4;

  const __hip_bfloat16* pA  = gs + (size_t)(m0 + r) * NG + kg * 8;
  const __hip_bfloat16* pb0 = Wd + (size_t)(nh * 64 + r) * NG + kg * 8;
  const __hip_bfloat16* pb1 = pb0 + (size_t)16 * NG;
  const __hip_bfloat16* pb2 = pb0 + (size_t)32 * NG;
  const __hip_bfloat16* pb3 = pb0 + (size_t)48 * NG;

  f32x4 a0{}, a1{}, a2{}, a3{};
  bf16x8 cA  = *(const bf16x8*)pA;
  bf16x8 cb0 = *(const bf16x8*)pb0;
  bf16x8 cb1 = *(const bf16x8*)pb1;
  bf16x8 cb2 = *(const bf16x8*)pb2;
  bf16x8 cb3 = *(const bf16x8*)pb3;
  #pragma unroll 4
  for (int c = 0; c < 127; ++c) {
    bf16x8 nA  = *(const bf16x8*)(pA  + (c + 1) * 32);
    bf16x8 nb0 = *(const bf16x8*)(pb0 + (c + 1) * 32);
    bf16x8 nb1 = *(const bf16x8*)(pb1 + (c + 1) * 32);
    bf16x8 nb2 = *(const bf16x8*)(pb2 + (c + 1) * 32);
    bf16x8 nb3 = *(const bf16x8*)(pb3 + (c + 1) * 32);
    a0 = mfma_bf16(cA, cb0, a0);
    a1 = mfma_bf16(cA, cb1, a1);
    a2 = mfma_bf16(cA, cb2, a2);
    a3 = mfma_bf16(cA, cb3, a3);
    cA = nA; cb0 = nb0; cb1 = nb1; cb2 = nb2; cb3 = nb3;
  }
  a0 = mfma_bf16(cA, cb0, a0);
  a1 = mfma_bf16(cA, cb1, a1);
  a2 = mfma_bf16(cA, cb2, a2);
  a3 = mfma_bf16(cA, cb3, a3);

  #pragma unroll
  for (int j = 0; j < 4; ++j) {
    float* sr = &sC[kg * 4 + j][nh * 64 + r];
    sr[0]  = a0[j];
    sr[16] = a1[j];
    sr[32] = a2[j];
    sr[48] = a3[j];
  }
  __syncthreads();

  // ---- log_softmax: wave nh handles rows 2*nh and 2*nh+1 ----
  #pragma unroll
  for (int mi = 0; mi < 2; ++mi) {
    const int m = nh * 2 + mi;
    float x[8];
    float mx = -3.4e38f;
    #pragma unroll
    for (int i = 0; i < 8; ++i) {
      x[i] = sC[m][lane + 64 * i];
      mx = fmaxf(mx, x[i]);
    }
    #pragma unroll
    for (int off = 32; off >= 1; off >>= 1) mx = fmaxf(mx, __shfl_xor(mx, off));
    float e = 0.f;
    #pragma unroll
    for (int i = 0; i < 8; ++i) e += __expf(x[i] - mx);
    #pragma unroll
    for (int off = 32; off >= 1; off >>= 1) e += __shfl_xor(e, off);
    const float lse = mx + __logf(e);
    float* po = out + (size_t)(m0 + m) * NP + lane;
    #pragma unroll
    for (int i = 0; i < 8; ++i) po[64 * i] = x[i] - lse;
  }
}

extern "C" void kernel_launch(void* const* d_in, const int* in_sizes, int n_in,
                              void* d_out, int out_size, void* d_ws, size_t ws_size,
                              hipStream_t stream) {
  const float* v    = (const float*)d_in[0];  // [64,100,2]
  const float* p0   = (const float*)d_in[1];  // [64,512]
  const float* Wenc = (const float*)d_in[2];  // [4096,512]
  const float* Win  = (const float*)d_in[3];  // [4096,2]
  const float* Wh   = (const float*)d_in[4];  // [4096,4096]
  const float* Wdec = (const float*)d_in[5];  // [512,4096]
  float* out = (float*)d_out;                 // [64,100,512]

  char* ws = (char*)d_ws;
  __hip_bfloat16* gs      = (__hip_bfloat16*)(ws);               // 52,428,800
  __hip_bfloat16* Wh_bf   = (__hip_bfloat16*)(ws + 52428800);    // 33,554,432
  __hip_bfloat16* Wdec_bf = (__hip_bfloat16*)(ws + 85983232);    //  4,194,304
  float*          vv      = (float*)(ws + 90177536);             //  1,048,576
  float*          zp      = (float*)(ws + 91226112);             //  1,048,576
  __hip_bfloat16* h0_bf   = (__hip_bfloat16*)(ws + 92274688);    //    524,288
  // total 92,798,976 B

  hipMemsetAsync(vv, 0, 2 * 1048576, stream);   // vv + zp (contiguous)
  cvt_bf16_kernel<<<8192, 256, 0, stream>>>(Wh, Wh_bf, 2097152);
  cvt_bf16_kernel<<<1024, 256, 0, stream>>>(Wdec, Wdec_bf, 262144);
  encoder_kernel<<<256, 256, 0, stream>>>(p0, Wenc, h0_bf);

  for (int t = 0; t < T_STEPS; ++t) {
    const __hip_bfloat16* A = (t == 0) ? h0_bf : (gs + (size_t)(t - 1) * NG);
    int sA = (t == 0) ? NG : T_STEPS * NG;
    rnn_step_kernel<<<dim3(128, 4), 512, 0, stream>>>(
        A, sA, Wh_bf, v, Win, vv, zp, gs, t);
  }

  decoder_softmax_kernel<<<400, 512, 0, stream>>>(gs, Wdec_bf, out);
}

// Round 7
// 3055.314 us; speedup vs baseline: 4.8720x; 1.0995x over previous
//
#include <hip/hip_runtime.h>
#include <hip/hip_bf16.h>

#define T_STEPS 100
#define NG 4096
#define NP 512

typedef __bf16 bf16x8 __attribute__((ext_vector_type(8)));
typedef float f32x4 __attribute__((ext_vector_type(4)));

__device__ __forceinline__ f32x4 mfma_bf16(bf16x8 a, bf16x8 b, f32x4 c) {
  return __builtin_amdgcn_mfma_f32_16x16x32_bf16(a, b, c, 0, 0, 0);
}

// ---------------- f32 -> bf16 conversion, 8 elems/thread ----------------
__global__ __launch_bounds__(256) void cvt_bf16_kernel(const float* __restrict__ in,
                                                       __hip_bfloat16* __restrict__ out,
                                                       int n8) {
  int i = blockIdx.x * 256 + threadIdx.x;
  if (i >= n8) return;
  const float4* p = reinterpret_cast<const float4*>(in) + (size_t)i * 2;
  float4 f0 = p[0], f1 = p[1];
  union { __hip_bfloat16 h[8]; uint4 u; } z;
  z.h[0] = __float2bfloat16(f0.x); z.h[1] = __float2bfloat16(f0.y);
  z.h[2] = __float2bfloat16(f0.z); z.h[3] = __float2bfloat16(f0.w);
  z.h[4] = __float2bfloat16(f1.x); z.h[5] = __float2bfloat16(f1.y);
  z.h[6] = __float2bfloat16(f1.z); z.h[7] = __float2bfloat16(f1.w);
  *(reinterpret_cast<uint4*>(out) + i) = z.u;
}

// ---------------- encoder: h0 = p0 @ W_enc^T  -> bf16 -------------------
__global__ __launch_bounds__(256) void encoder_kernel(const float* __restrict__ p0,
                                                      const float* __restrict__ Wenc,
                                                      __hip_bfloat16* __restrict__ h0) {
  __shared__ float sp[64 * 129];
  const int tid = threadIdx.x;
  const int nb = blockIdx.x * 16;
  const int b = tid & 63;
  const int jg = tid >> 6;
  float acc[4] = {0.f, 0.f, 0.f, 0.f};
  for (int kc = 0; kc < NP; kc += 128) {
    __syncthreads();
    #pragma unroll
    for (int i = 0; i < 32; ++i) {
      int e = tid + i * 256;
      int bb = e >> 7, kk = e & 127;
      sp[bb * 129 + kk] = p0[bb * NP + kc + kk];
    }
    __syncthreads();
    for (int kk = 0; kk < 128; ++kk) {
      float pv = sp[b * 129 + kk];
      #pragma unroll
      for (int jj = 0; jj < 4; ++jj)
        acc[jj] += pv * Wenc[(size_t)(nb + jg * 4 + jj) * NP + kc + kk];
    }
  }
  #pragma unroll
  for (int jj = 0; jj < 4; ++jj)
    h0[(size_t)b * NG + nb + jg * 4 + jj] = __float2bfloat16(acc[jj]);
}

// ---------------- RNN GEMM partial: zpart[kq] = A_kslice @ Wh_kslice^T --
// grid (128 ng, 8 kq) = 1024 blocks (4/CU, 16 waves/CU), block 256 = 4 waves.
// Wave ms owns b-rows [16ms, +16); block owns n [32ng, +32), k [512kq, +512).
// Wave tile 16b x 32n x 512k: per iter 3 loads (A, B0, B1) + 2 MFMA.
// 2-deep statically-indexed ping-pong prefetch (full unroll => regs).
// XCD note: linear%8 = ng%8, so each XCD re-reads the same Wh columns every
// step across all kq -> its 4 MiB slice stays L2-resident across launches.
__global__ __launch_bounds__(256, 4) void rnn_gemm_kernel(
    const __hip_bfloat16* __restrict__ A, int strideA,
    const __hip_bfloat16* __restrict__ Wh,
    float* __restrict__ zpart) {
  const int lane = threadIdx.x & 63;
  const int ms = threadIdx.x >> 6;    // b-strip 0..3
  const int ng = blockIdx.x, kq = blockIdx.y;
  const int r = lane & 15;
  const int kg = lane >> 4;
  const int kbase = kq * 512 + kg * 8;
  const int n0 = ng * 32;

  const __hip_bfloat16* pA  = A  + (size_t)(ms * 16 + r) * strideA + kbase;
  const __hip_bfloat16* pB0 = Wh + (size_t)(n0 + r) * NG + kbase;
  const __hip_bfloat16* pB1 = pB0 + (size_t)16 * NG;

  f32x4 acc0{}, acc1{};
  bf16x8 Ab[2], B0b[2], B1b[2];
  Ab[0]  = *(const bf16x8*)(pA);
  B0b[0] = *(const bf16x8*)(pB0);
  B1b[0] = *(const bf16x8*)(pB1);
  Ab[1]  = *(const bf16x8*)(pA  + 32);
  B0b[1] = *(const bf16x8*)(pB0 + 32);
  B1b[1] = *(const bf16x8*)(pB1 + 32);
  #pragma unroll
  for (int it = 0; it < 16; ++it) {
    const int s = it & 1;             // compile-time after full unroll
    bf16x8 a = Ab[s], b0 = B0b[s], b1 = B1b[s];
    if (it < 14) {
      Ab[s]  = *(const bf16x8*)(pA  + (it + 2) * 32);
      B0b[s] = *(const bf16x8*)(pB0 + (it + 2) * 32);
      B1b[s] = *(const bf16x8*)(pB1 + (it + 2) * 32);
    }
    acc0 = mfma_bf16(a, b0, acc0);
    acc1 = mfma_bf16(a, b1, acc1);
  }

  // store partial: row b = ms*16 + kg*4 + j, col n = n0 + {r, r+16}
  float* zb = zpart + ((size_t)(kq * 64 + ms * 16 + kg * 4) << 12) + n0 + r;
  #pragma unroll
  for (int j = 0; j < 4; ++j) {
    zb[(size_t)j * NG]      = acc0[j];
    zb[(size_t)j * NG + 16] = acc1[j];
  }
}

// ---------------- RNN epilogue: sum partials + recurrence + relu --------
// grid 256 x 256 thr; thread handles 4 consecutive n of one b.
__global__ __launch_bounds__(256) void rnn_epi_kernel(
    const float* __restrict__ zpart,
    const float* __restrict__ v, const float* __restrict__ Win,
    float* __restrict__ vv, float* __restrict__ zp,
    __hip_bfloat16* __restrict__ gs, int t) {
  const int g = blockIdx.x * 256 + threadIdx.x;   // 0..65535
  const int b = g >> 10;
  const int n = (g & 1023) * 4;
  f32x4 s{};
  #pragma unroll
  for (int kq = 0; kq < 8; ++kq)
    s += *(const f32x4*)(zpart + ((size_t)(kq * 64 + b) << 12) + n);
  float2 vt = *(const float2*)(v + (b * T_STEPS + t) * 2);
  float4 wA = *(const float4*)(Win + 2 * n);
  float4 wB = *(const float4*)(Win + 2 * n + 4);
  f32x4 z;
  z[0] = s[0] + vt.x * wA.x + vt.y * wA.y;
  z[1] = s[1] + vt.x * wA.z + vt.y * wA.w;
  z[2] = s[2] + vt.x * wB.x + vt.y * wB.y;
  z[3] = s[3] + vt.x * wB.z + vt.y * wB.w;
  f32x4 vvo = *(const f32x4*)(vv + (size_t)b * NG + n);
  f32x4 zpo = *(const f32x4*)(zp + (size_t)b * NG + n);
  union { __hip_bfloat16 h[4]; uint2 u2; } o;
  f32x4 vvn;
  #pragma unroll
  for (int j = 0; j < 4; ++j) {
    z[j] -= 0.5f * vvo[j];                       // z uses OLD vv
    vvn[j] = fmaxf(vvo[j] + 0.1f * (zpo[j] - vvo[j]), 0.f);
    o.h[j] = __float2bfloat16(fmaxf(z[j], 0.f));
  }
  *(f32x4*)(vv + (size_t)b * NG + n) = vvn;
  *(f32x4*)(zp + (size_t)b * NG + n) = z;        // pre-relu z
  *(uint2*)(gs + (size_t)(b * T_STEPS + t) * NG + n) = o.u2;
}

// ---------------- decoder + fused log_softmax ---------------------------
// grid 400 m-tiles of 16 rows; block 256 = 4 waves, wave nh owns 128 n-cols
// (8 frags: 9 loads -> 8 MFMA per iter, 2-deep ping-pong prefetch).
// gs read exactly once; Wd (4 MiB) L2-resident per XCD. Logits staged in
// 32 KB LDS, per-row shuffle log_softmax (wave nh does rows 4nh..4nh+3).
__global__ __launch_bounds__(256) void decoder_softmax_kernel(
    const __hip_bfloat16* __restrict__ gs,
    const __hip_bfloat16* __restrict__ Wd,
    float* __restrict__ out) {
  __shared__ float sC[16][NP];
  const int tid = threadIdx.x;
  const int lane = tid & 63;
  const int nh = tid >> 6;        // wave id = n-chunk of 128
  const int m0 = blockIdx.x * 16;
  const int r = lane & 15;
  const int kg = lane >> 4;

  const __hip_bfloat16* pA = gs + (size_t)(m0 + r) * NG + kg * 8;
  const __hip_bfloat16* pB[8];
  #pragma unroll
  for (int i = 0; i < 8; ++i)
    pB[i] = Wd + (size_t)(nh * 128 + i * 16 + r) * NG + kg * 8;

  f32x4 acc[8] = {};
  bf16x8 A0, A1, B0[8], B1[8];
  A0 = *(const bf16x8*)(pA);
  A1 = *(const bf16x8*)(pA + 32);
  #pragma unroll
  for (int i = 0; i < 8; ++i) {
    B0[i] = *(const bf16x8*)(pB[i]);
    B1[i] = *(const bf16x8*)(pB[i] + 32);
  }
  for (int c = 0; c < 128; c += 2) {
    // even slot: consume (A0,B0)=iter c, prefetch iter c+2
    {
      bf16x8 a = A0;
      bf16x8 bcur[8];
      #pragma unroll
      for (int i = 0; i < 8; ++i) bcur[i] = B0[i];
      if (c + 2 < 128) {
        A0 = *(const bf16x8*)(pA + (c + 2) * 32);
        #pragma unroll
        for (int i = 0; i < 8; ++i) B0[i] = *(const bf16x8*)(pB[i] + (c + 2) * 32);
      }
      #pragma unroll
      for (int i = 0; i < 8; ++i) acc[i] = mfma_bf16(a, bcur[i], acc[i]);
    }
    // odd slot: consume (A1,B1)=iter c+1, prefetch iter c+3
    {
      bf16x8 a = A1;
      bf16x8 bcur[8];
      #pragma unroll
      for (int i = 0; i < 8; ++i) bcur[i] = B1[i];
      if (c + 3 < 128) {
        A1 = *(const bf16x8*)(pA + (c + 3) * 32);
        #pragma unroll
        for (int i = 0; i < 8; ++i) B1[i] = *(const bf16x8*)(pB[i] + (c + 3) * 32);
      }
      #pragma unroll
      for (int i = 0; i < 8; ++i) acc[i] = mfma_bf16(a, bcur[i], acc[i]);
    }
  }

  #pragma unroll
  for (int j = 0; j < 4; ++j) {
    float* sr = &sC[kg * 4 + j][nh * 128 + r];
    #pragma unroll
    for (int i = 0; i < 8; ++i) sr[16 * i] = acc[i][j];
  }
  __syncthreads();

  // ---- log_softmax: wave nh handles rows 4nh .. 4nh+3 ----
  #pragma unroll
  for (int mi = 0; mi < 4; ++mi) {
    const int m = nh * 4 + mi;
    float x[8];
    float mx = -3.4e38f;
    #pragma unroll
    for (int i = 0; i < 8; ++i) {
      x[i] = sC[m][lane + 64 * i];
      mx = fmaxf(mx, x[i]);
    }
    #pragma unroll
    for (int off = 32; off >= 1; off >>= 1) mx = fmaxf(mx, __shfl_xor(mx, off));
    float e = 0.f;
    #pragma unroll
    for (int i = 0; i < 8; ++i) e += __expf(x[i] - mx);
    #pragma unroll
    for (int off = 32; off >= 1; off >>= 1) e += __shfl_xor(e, off);
    const float lse = mx + __logf(e);
    float* po = out + (size_t)(m0 + m) * NP + lane;
    #pragma unroll
    for (int i = 0; i < 8; ++i) po[64 * i] = x[i] - lse;
  }
}

extern "C" void kernel_launch(void* const* d_in, const int* in_sizes, int n_in,
                              void* d_out, int out_size, void* d_ws, size_t ws_size,
                              hipStream_t stream) {
  const float* v    = (const float*)d_in[0];  // [64,100,2]
  const float* p0   = (const float*)d_in[1];  // [64,512]
  const float* Wenc = (const float*)d_in[2];  // [4096,512]
  const float* Win  = (const float*)d_in[3];  // [4096,2]
  const float* Wh   = (const float*)d_in[4];  // [4096,4096]
  const float* Wdec = (const float*)d_in[5];  // [512,4096]
  float* out = (float*)d_out;                 // [64,100,512]

  char* ws = (char*)d_ws;
  __hip_bfloat16* gs      = (__hip_bfloat16*)(ws);               // 52,428,800
  __hip_bfloat16* Wh_bf   = (__hip_bfloat16*)(ws + 52428800);    // 33,554,432
  float*          zpart   = (float*)(ws + 85983232);             //  8,388,608
  __hip_bfloat16* Wdec_bf = (__hip_bfloat16*)(ws + 85983232);    // aliases zpart (used after RNN)
  float*          vv      = (float*)(ws + 94371840);             //  1,048,576
  float*          zp      = (float*)(ws + 95420416);             //  1,048,576
  __hip_bfloat16* h0_bf   = (__hip_bfloat16*)(ws + 96468992);    //    524,288
  // total 96,993,280 B

  hipMemsetAsync(vv, 0, 2 * 1048576, stream);   // vv + zp (contiguous)
  cvt_bf16_kernel<<<8192, 256, 0, stream>>>(Wh, Wh_bf, 2097152);
  encoder_kernel<<<256, 256, 0, stream>>>(p0, Wenc, h0_bf);

  for (int t = 0; t < T_STEPS; ++t) {
    const __hip_bfloat16* A = (t == 0) ? h0_bf : (gs + (size_t)(t - 1) * NG);
    int sA = (t == 0) ? NG : T_STEPS * NG;
    rnn_gemm_kernel<<<dim3(128, 8), 256, 0, stream>>>(A, sA, Wh_bf, zpart);
    rnn_epi_kernel<<<256, 256, 0, stream>>>(zpart, v, Win, vv, zp, gs, t);
  }

  cvt_bf16_kernel<<<1024, 256, 0, stream>>>(Wdec, Wdec_bf, 262144);  // after RNN (aliases zpart)
  decoder_softmax_kernel<<<400, 256, 0, stream>>>(gs, Wdec_bf, out);
}

// Round 8
// 2337.367 us; speedup vs baseline: 6.3685x; 1.3072x over previous
//
#include <hip/hip_runtime.h>
#include <hip/hip_bf16.h>

#define T_STEPS 100
#define NG 4096
#define NP 512

typedef __bf16 bf16x8 __attribute__((ext_vector_type(8)));
typedef float f32x4 __attribute__((ext_vector_type(4)));

__device__ __forceinline__ f32x4 mfma_bf16(bf16x8 a, bf16x8 b, f32x4 c) {
  return __builtin_amdgcn_mfma_f32_16x16x32_bf16(a, b, c, 0, 0, 0);
}

// ---------------- f32 -> bf16 conversion, 8 elems/thread ----------------
__global__ __launch_bounds__(256) void cvt_bf16_kernel(const float* __restrict__ in,
                                                       __hip_bfloat16* __restrict__ out,
                                                       int n8) {
  int i = blockIdx.x * 256 + threadIdx.x;
  if (i >= n8) return;
  const float4* p = reinterpret_cast<const float4*>(in) + (size_t)i * 2;
  float4 f0 = p[0], f1 = p[1];
  union { __hip_bfloat16 h[8]; uint4 u; } z;
  z.h[0] = __float2bfloat16(f0.x); z.h[1] = __float2bfloat16(f0.y);
  z.h[2] = __float2bfloat16(f0.z); z.h[3] = __float2bfloat16(f0.w);
  z.h[4] = __float2bfloat16(f1.x); z.h[5] = __float2bfloat16(f1.y);
  z.h[6] = __float2bfloat16(f1.z); z.h[7] = __float2bfloat16(f1.w);
  *(reinterpret_cast<uint4*>(out) + i) = z.u;
}

// ---------------- encoder: h0 = p0 @ W_enc^T  -> bf16 -------------------
__global__ __launch_bounds__(256) void encoder_kernel(const float* __restrict__ p0,
                                                      const float* __restrict__ Wenc,
                                                      __hip_bfloat16* __restrict__ h0) {
  __shared__ float sp[64 * 129];
  const int tid = threadIdx.x;
  const int nb = blockIdx.x * 16;
  const int b = tid & 63;
  const int jg = tid >> 6;
  float acc[4] = {0.f, 0.f, 0.f, 0.f};
  for (int kc = 0; kc < NP; kc += 128) {
    __syncthreads();
    #pragma unroll
    for (int i = 0; i < 32; ++i) {
      int e = tid + i * 256;
      int bb = e >> 7, kk = e & 127;
      sp[bb * 129 + kk] = p0[bb * NP + kc + kk];
    }
    __syncthreads();
    for (int kk = 0; kk < 128; ++kk) {
      float pv = sp[b * 129 + kk];
      #pragma unroll
      for (int jj = 0; jj < 4; ++jj)
        acc[jj] += pv * Wenc[(size_t)(nb + jg * 4 + jj) * NP + kc + kk];
    }
  }
  #pragma unroll
  for (int jj = 0; jj < 4; ++jj)
    h0[(size_t)b * NG + nb + jg * 4 + jj] = __float2bfloat16(acc[jj]);
}

// ---------------- RNN GEMM partial (round-4 verbatim, best measured) ----
// grid (64 ng, 8 kq), block 256 thr = 4 waves (ms = w>>1: 32 b-rows;
// ns = w&1: 32 n-cols). Wave tile 32b x 32n x 512k, 2x2 frags = 4 indep
// MFMA chains (>=4 required to cover MFMA dep latency), 4 loads : 4 MFMA.
__global__ __launch_bounds__(256, 2) void rnn_gemm_kernel(
    const __hip_bfloat16* __restrict__ A, int strideA,
    const __hip_bfloat16* __restrict__ Wh,
    float* __restrict__ zpart) {
  const int lane = threadIdx.x & 63;
  const int w = threadIdx.x >> 6;
  const int ms = w >> 1, ns = w & 1;
  const int ng = blockIdx.x, kq = blockIdx.y;
  const int r = lane & 15;       // row within 16-frag (b for A, n for B)
  const int kg = lane >> 4;      // k-group
  const int kbase = kq * 512 + kg * 8;
  const int n0 = ng * 64 + ns * 32;

  const __hip_bfloat16* pA0 = A + (size_t)(ms * 32 + r) * strideA + kbase;
  const __hip_bfloat16* pA1 = pA0 + (size_t)16 * strideA;
  const __hip_bfloat16* pB0 = Wh + (size_t)(n0 + r) * NG + kbase;
  const __hip_bfloat16* pB1 = pB0 + (size_t)16 * NG;

  f32x4 acc00{}, acc01{}, acc10{}, acc11{};
  bf16x8 cA0 = *(const bf16x8*)(pA0);
  bf16x8 cA1 = *(const bf16x8*)(pA1);
  bf16x8 cB0 = *(const bf16x8*)(pB0);
  bf16x8 cB1 = *(const bf16x8*)(pB1);
  #pragma unroll
  for (int it = 0; it < 16; ++it) {
    bf16x8 nA0, nA1, nB0, nB1;
    if (it < 15) {
      nA0 = *(const bf16x8*)(pA0 + (it + 1) * 32);
      nA1 = *(const bf16x8*)(pA1 + (it + 1) * 32);
      nB0 = *(const bf16x8*)(pB0 + (it + 1) * 32);
      nB1 = *(const bf16x8*)(pB1 + (it + 1) * 32);
    }
    acc00 = mfma_bf16(cA0, cB0, acc00);
    acc01 = mfma_bf16(cA0, cB1, acc01);
    acc10 = mfma_bf16(cA1, cB0, acc10);
    acc11 = mfma_bf16(cA1, cB1, acc11);
    if (it < 15) { cA0 = nA0; cA1 = nA1; cB0 = nB0; cB1 = nB1; }
  }

  // store: C row b = ms*32 + fi*16 + (lane>>4)*4 + j; col n = n0 + fj*16 + r
  float* zb = zpart + ((size_t)(kq * 64 + ms * 32 + kg * 4) << 12) + n0 + r;
  #pragma unroll
  for (int j = 0; j < 4; ++j) {
    zb[(size_t)j * NG]                    = acc00[j];
    zb[(size_t)j * NG + 16]               = acc01[j];
    zb[(size_t)(16 + j) * NG]             = acc10[j];
    zb[(size_t)(16 + j) * NG + 16]        = acc11[j];
  }
}

// ---------------- RNN epilogue: sum partials + recurrence + relu --------
// grid 256 x 256 thr; thread handles 4 consecutive n of one b.
__global__ __launch_bounds__(256) void rnn_epi_kernel(
    const float* __restrict__ zpart,
    const float* __restrict__ v, const float* __restrict__ Win,
    float* __restrict__ vv, float* __restrict__ zp,
    __hip_bfloat16* __restrict__ gs, int t) {
  const int g = blockIdx.x * 256 + threadIdx.x;   // 0..65535
  const int b = g >> 10;
  const int n = (g & 1023) * 4;
  f32x4 s{};
  #pragma unroll
  for (int kq = 0; kq < 8; ++kq)
    s += *(const f32x4*)(zpart + ((size_t)(kq * 64 + b) << 12) + n);
  float2 vt = *(const float2*)(v + (b * T_STEPS + t) * 2);
  float4 wA = *(const float4*)(Win + 2 * n);
  float4 wB = *(const float4*)(Win + 2 * n + 4);
  f32x4 z;
  z[0] = s[0] + vt.x * wA.x + vt.y * wA.y;
  z[1] = s[1] + vt.x * wA.z + vt.y * wA.w;
  z[2] = s[2] + vt.x * wB.x + vt.y * wB.y;
  z[3] = s[3] + vt.x * wB.z + vt.y * wB.w;
  f32x4 vvo = *(const f32x4*)(vv + (size_t)b * NG + n);
  f32x4 zpo = *(const f32x4*)(zp + (size_t)b * NG + n);
  union { __hip_bfloat16 h[4]; uint2 u2; } o;
  f32x4 vvn;
  #pragma unroll
  for (int j = 0; j < 4; ++j) {
    z[j] -= 0.5f * vvo[j];                       // z uses OLD vv
    vvn[j] = fmaxf(vvo[j] + 0.1f * (zpo[j] - vvo[j]), 0.f);
    o.h[j] = __float2bfloat16(fmaxf(z[j], 0.f));
  }
  *(f32x4*)(vv + (size_t)b * NG + n) = vvn;
  *(f32x4*)(zp + (size_t)b * NG + n) = z;        // pre-relu z
  *(uint2*)(gs + (size_t)(b * T_STEPS + t) * NG + n) = o.u2;
}

// ---------------- decoder: logits = gs @ W_dec^T ------------------------
// grid (400 m-tiles of 16, 4 n-slices of 128) = 1600 blocks (~6/CU).
// Block 256 thr = 4 waves, wave kh owns a 1024-k quarter: 8 B-chains,
// 9 loads : 8 MFMA, 2-deep ping-pong prefetch. k-quarters reduced via
// 24 KB LDS. XCD = m-tile%8 (gridDim.x=400, 400%8=0): an m-tile's 4
// n-blocks share one XCD's L2 (gs row fetched once, used 4x); Wd (4 MB)
// L2-resident per XCD.
__global__ __launch_bounds__(256) void decoder_kernel(
    const __hip_bfloat16* __restrict__ gs,
    const __hip_bfloat16* __restrict__ Wd,
    float* __restrict__ out) {
  __shared__ float sred[3][16][128];
  const int tid = threadIdx.x;
  const int lane = tid & 63;
  const int kh = tid >> 6;        // wave id = k-quarter
  const int m0 = blockIdx.x * 16;
  const int n0 = blockIdx.y * 128;
  const int r = lane & 15;
  const int kg = lane >> 4;

  const __hip_bfloat16* pA = gs + (size_t)(m0 + r) * NG + kh * 1024 + kg * 8;
  const __hip_bfloat16* pB[8];
  #pragma unroll
  for (int i = 0; i < 8; ++i)
    pB[i] = Wd + (size_t)(n0 + i * 16 + r) * NG + kh * 1024 + kg * 8;

  f32x4 acc[8] = {};
  bf16x8 A0, A1, B0[8], B1[8];
  A0 = *(const bf16x8*)(pA);
  A1 = *(const bf16x8*)(pA + 32);
  #pragma unroll
  for (int i = 0; i < 8; ++i) {
    B0[i] = *(const bf16x8*)(pB[i]);
    B1[i] = *(const bf16x8*)(pB[i] + 32);
  }
  for (int c = 0; c < 32; c += 2) {
    // even slot: consume iter c, prefetch iter c+2
    {
      bf16x8 a = A0;
      bf16x8 bcur[8];
      #pragma unroll
      for (int i = 0; i < 8; ++i) bcur[i] = B0[i];
      if (c + 2 < 32) {
        A0 = *(const bf16x8*)(pA + (c + 2) * 32);
        #pragma unroll
        for (int i = 0; i < 8; ++i) B0[i] = *(const bf16x8*)(pB[i] + (c + 2) * 32);
      }
      #pragma unroll
      for (int i = 0; i < 8; ++i) acc[i] = mfma_bf16(a, bcur[i], acc[i]);
    }
    // odd slot: consume iter c+1, prefetch iter c+3
    {
      bf16x8 a = A1;
      bf16x8 bcur[8];
      #pragma unroll
      for (int i = 0; i < 8; ++i) bcur[i] = B1[i];
      if (c + 3 < 32) {
        A1 = *(const bf16x8*)(pA + (c + 3) * 32);
        #pragma unroll
        for (int i = 0; i < 8; ++i) B1[i] = *(const bf16x8*)(pB[i] + (c + 3) * 32);
      }
      #pragma unroll
      for (int i = 0; i < 8; ++i) acc[i] = mfma_bf16(a, bcur[i], acc[i]);
    }
  }

  if (kh > 0) {
    #pragma unroll
    for (int j = 0; j < 4; ++j)
      #pragma unroll
      for (int i = 0; i < 8; ++i)
        sred[kh - 1][kg * 4 + j][i * 16 + r] = acc[i][j];
  }
  __syncthreads();
  if (kh == 0) {
    #pragma unroll
    for (int j = 0; j < 4; ++j) {
      const int row = kg * 4 + j;
      float* po = out + (size_t)(m0 + row) * NP + n0;
      #pragma unroll
      for (int i = 0; i < 8; ++i) {
        const int col = i * 16 + r;
        po[col] = acc[i][j] + sred[0][row][col] + sred[1][row][col]
                            + sred[2][row][col];
      }
    }
  }
}

// ---------------- log_softmax over rows of 512 (in place) ---------------
__global__ __launch_bounds__(256) void logsoftmax_kernel(float* __restrict__ out) {
  float* row = out + (size_t)blockIdx.x * NP;
  const int tid = threadIdx.x;
  const int lane = tid & 63, wid = tid >> 6;
  float x0 = row[tid], x1 = row[tid + 256];
  float m = fmaxf(x0, x1);
  #pragma unroll
  for (int off = 32; off >= 1; off >>= 1) m = fmaxf(m, __shfl_xor(m, off));
  __shared__ float sred[8];
  if (lane == 0) sred[wid] = m;
  __syncthreads();
  m = fmaxf(fmaxf(sred[0], sred[1]), fmaxf(sred[2], sred[3]));
  float e = __expf(x0 - m) + __expf(x1 - m);
  #pragma unroll
  for (int off = 32; off >= 1; off >>= 1) e += __shfl_xor(e, off);
  if (lane == 0) sred[4 + wid] = e;
  __syncthreads();
  float lse = m + __logf(sred[4] + sred[5] + sred[6] + sred[7]);
  row[tid] = x0 - lse;
  row[tid + 256] = x1 - lse;
}

extern "C" void kernel_launch(void* const* d_in, const int* in_sizes, int n_in,
                              void* d_out, int out_size, void* d_ws, size_t ws_size,
                              hipStream_t stream) {
  const float* v    = (const float*)d_in[0];  // [64,100,2]
  const float* p0   = (const float*)d_in[1];  // [64,512]
  const float* Wenc = (const float*)d_in[2];  // [4096,512]
  const float* Win  = (const float*)d_in[3];  // [4096,2]
  const float* Wh   = (const float*)d_in[4];  // [4096,4096]
  const float* Wdec = (const float*)d_in[5];  // [512,4096]
  float* out = (float*)d_out;                 // [64,100,512]

  char* ws = (char*)d_ws;
  __hip_bfloat16* gs      = (__hip_bfloat16*)(ws);               // 52,428,800
  __hip_bfloat16* Wh_bf   = (__hip_bfloat16*)(ws + 52428800);    // 33,554,432
  float*          zpart   = (float*)(ws + 85983232);             //  8,388,608
  __hip_bfloat16* Wdec_bf = (__hip_bfloat16*)(ws + 85983232);    // aliases zpart (used after RNN)
  float*          vv      = (float*)(ws + 94371840);             //  1,048,576
  float*          zp      = (float*)(ws + 95420416);             //  1,048,576
  __hip_bfloat16* h0_bf   = (__hip_bfloat16*)(ws + 96468992);    //    524,288
  // total 96,993,280 B

  hipMemsetAsync(vv, 0, 2 * 1048576, stream);   // vv + zp (contiguous)
  cvt_bf16_kernel<<<8192, 256, 0, stream>>>(Wh, Wh_bf, 2097152);
  encoder_kernel<<<256, 256, 0, stream>>>(p0, Wenc, h0_bf);

  for (int t = 0; t < T_STEPS; ++t) {
    const __hip_bfloat16* A = (t == 0) ? h0_bf : (gs + (size_t)(t - 1) * NG);
    int sA = (t == 0) ? NG : T_STEPS * NG;
    rnn_gemm_kernel<<<dim3(64, 8), 256, 0, stream>>>(A, sA, Wh_bf, zpart);
    rnn_epi_kernel<<<256, 256, 0, stream>>>(zpart, v, Win, vv, zp, gs, t);
  }

  cvt_bf16_kernel<<<1024, 256, 0, stream>>>(Wdec, Wdec_bf, 262144);  // after RNN (aliases zpart)
  decoder_kernel<<<dim3(400, 4), 256, 0, stream>>>(gs, Wdec_bf, out);
  logsoftmax_kernel<<<6400, 256, 0, stream>>>(out);
}